// Round 5
// baseline (277.680 us; speedup 1.0000x reference)
//
#include <hip/hip_runtime.h>
#include <cstddef>

#define N_NODES 65536
#define NPER    1024
#define NGRAPH  64
#define HID     64
#define IN_F    128
#define KCLUS   16
#define NCLS    10
#define ECAP    20480   // per-graph capacity incl. 4-alignment padding
#define ZROW    NPER    // sentinel index used by padding entries
#define LIN_BLOCKS 512  // N_NODES/128 tiles for the linear part of front_kernel

// ================================================================ GEMM tile core (verified round-0/3)
template <int K>
__device__ __forceinline__ void gemm_tile(const float* __restrict__ X,
                                          const float* __restrict__ W,
                                          float* __restrict__ Y,
                                          float (*xs)[68], float (*ws)[68],
                                          int block, int t) {
    const size_t row0 = (size_t)block * 128;
    const int rbase = t >> 3;   // 0..31
    const int cbase = t & 7;    // 0..7
    float acc[4][8] = {};

    for (int kc = 0; kc < K; kc += 64) {
        __syncthreads();
        for (int i = t; i < 128 * 16; i += 256) {   // X tile: 128 rows x 16 float4
            int row = i >> 4, k4 = (i & 15) << 2;
            *(float4*)&xs[row][k4] = *(const float4*)(X + (row0 + row) * K + kc + k4);
        }
        for (int i = t; i < 64 * 16; i += 256) {    // W tile: 64 rows x 16 float4
            int col = i >> 4, k4 = (i & 15) << 2;
            *(float4*)&ws[col][k4] = *(const float4*)(W + col * K + kc + k4);
        }
        __syncthreads();

#pragma unroll 4
        for (int k4 = 0; k4 < 64; k4 += 4) {
            float4 xr[4], wr[8];
#pragma unroll
            for (int rr = 0; rr < 4; ++rr) xr[rr] = *(const float4*)&xs[rbase + 32 * rr][k4];
#pragma unroll
            for (int cc = 0; cc < 8; ++cc) wr[cc] = *(const float4*)&ws[cbase + 8 * cc][k4];
#pragma unroll
            for (int rr = 0; rr < 4; ++rr)
#pragma unroll
                for (int cc = 0; cc < 8; ++cc) {
                    acc[rr][cc] = fmaf(xr[rr].x, wr[cc].x, acc[rr][cc]);
                    acc[rr][cc] = fmaf(xr[rr].y, wr[cc].y, acc[rr][cc]);
                    acc[rr][cc] = fmaf(xr[rr].z, wr[cc].z, acc[rr][cc]);
                    acc[rr][cc] = fmaf(xr[rr].w, wr[cc].w, acc[rr][cc]);
                }
        }
    }

#pragma unroll
    for (int rr = 0; rr < 4; ++rr)
#pragma unroll
        for (int cc = 0; cc < 8; ++cc)
            Y[(row0 + rbase + 32 * rr) * HID + cbase + 8 * cc] = acc[rr][cc];
}

// ---------------------------------------------------------------- front: linear1 (blocks 0..511) || bucket (blocks 512..) (verified round-0/3)
__global__ __launch_bounds__(256) void front_kernel(const float* __restrict__ X,
                                                    const float* __restrict__ W,
                                                    float* __restrict__ Y,
                                                    const int* __restrict__ src,
                                                    const int* __restrict__ dst,
                                                    int* __restrict__ ecnt,
                                                    int* __restrict__ gedges, int E) {
    __shared__ float xs[128][68];
    __shared__ float ws[64][68];
    const int t = threadIdx.x;

    if (blockIdx.x >= LIN_BLOCKS) {
        int* hist = (int*)&xs[0][0];
        int* base_l = hist + NGRAPH;
        const int e0 = (blockIdx.x - LIN_BLOCKS) * 1024;
        if (t < NGRAPH) hist[t] = 0;
        __syncthreads();

        int gg[4], rr[4], pk[4];
#pragma unroll
        for (int i = 0; i < 4; ++i) {
            int idx = e0 + i * 256 + t;
            if (idx < E) {
                int d = dst[idx], s = src[idx];
                int g = d >> 10;
                gg[i] = g;
                pk[i] = ((d & 1023) << 10) | (s & 1023);
                rr[i] = atomicAdd(&hist[g], 1);
            } else gg[i] = -1;
        }
        __syncthreads();
        if (t < NGRAPH) base_l[t] = atomicAdd(&ecnt[t], hist[t]);
        __syncthreads();
#pragma unroll
        for (int i = 0; i < 4; ++i) {
            if (gg[i] >= 0) {
                int pos = base_l[gg[i]] + rr[i];
                if (pos < ECAP) gedges[gg[i] * ECAP + pos] = pk[i];
            }
        }
        return;
    }

    gemm_tile<IN_F>(X, W, Y, xs, ws, blockIdx.x, t);
}

// ---------------------------------------------------------------- dense linear (conv2): Y = X @ W^T (verified)
template <int K>
__global__ __launch_bounds__(256) void linear_kernel(const float* __restrict__ X,
                                                     const float* __restrict__ W,
                                                     float* __restrict__ Y) {
    __shared__ float xs[128][68];
    __shared__ float ws[64][68];
    gemm_tile<K>(X, W, Y, xs, ws, blockIdx.x, threadIdx.x);
}

// ---------------------------------------------------------------- distributed CSR build, dst-range partitioned (verified round-3)
__global__ __launch_bounds__(1024) void scatter_kernel(const int* __restrict__ gedges,
                                                       const int* __restrict__ ecnt,
                                                       int* __restrict__ rp,
                                                       unsigned short* __restrict__ esorted,
                                                       float* __restrict__ dinv) {
    __shared__ int hist[NPER];
    __shared__ int wsum[16];
    const int g = blockIdx.x >> 3;
    const int sub = blockIdx.x & 7;          // owns dst rows [sub*128, sub*128+128)
    const int t = threadIdx.x;
    const int lane = t & 63, wid = t >> 6;
    const int ec = ecnt[g];
    const int* ge = gedges + (size_t)g * ECAP;

    hist[t] = 0;
    __syncthreads();
    for (int i = t; i < ec; i += 1024) atomicAdd(&hist[ge[i] >> 10], 1);
    __syncthreads();

    const int h0 = hist[t];
    const int pd = (h0 + 3) & ~3;   // padded degree
    int v = pd;
#pragma unroll
    for (int off = 1; off < 64; off <<= 1) {
        int x = __shfl_up(v, off, 64);
        if (lane >= off) v += x;
    }
    if (lane == 63) wsum[wid] = v;
    __syncthreads();
    if (wid == 0) {
        int wv = (lane < 16) ? wsum[lane] : 0;
#pragma unroll
        for (int off = 1; off < 16; off <<= 1) {
            int x = __shfl_up(wv, off, 64);
            if (lane >= off) wv += x;
        }
        if (lane < 16) wsum[lane] = wv;
    }
    __syncthreads();
    const int incl = v + (wid > 0 ? wsum[wid - 1] : 0);
    const int excl = incl - pd;

    if (sub == 0) {                          // one block per graph publishes rp/dinv
        rp[g * (NPER + 1) + t] = excl;
        if (t == NPER - 1) rp[g * (NPER + 1) + NPER] = incl;
        dinv[g * NPER + t] = rsqrtf((float)h0 + 1.0f);
    }
    __syncthreads();
    hist[t] = excl;                          // scatter cursor (row start)
    __syncthreads();

    unsigned short* es = esorted + (size_t)g * ECAP;

    // padding: thread t owns row t; gate to this block's row range
    if ((t >> 7) == sub)
        for (int q = excl + h0; q < excl + pd; ++q) es[q] = (unsigned short)ZROW;

    // scatter: only edges targeting this block's dst range, LDS cursors
    for (int i = t; i < ec; i += 1024) {
        int pk = ge[i];
        int d = pk >> 10;
        if ((d >> 7) == sub) {
            int pos = atomicAdd(&hist[d], 1);
            es[pos] = (unsigned short)(pk & 1023);
        }
    }
}

// ---------------------------------------------------------------- L2-direct aggregation (NEW)
// 64 graphs x 4 feature-slices of 16 (one 64B cache line per edge per block).
// One dst row per thread, neighbor rows read straight from L2 (per-graph h
// slice = 256 KB, L2-resident; staging it in LDS was pure overhead + bank
// conflicts). dinv[src] applied at gather time (4 KB/graph, L1-resident).
// Padding entries (ZROW) handled branch-free: clamped index, zero coefficient.
__global__ __launch_bounds__(1024) void agg_kernel(const float* __restrict__ h,
                                                   const unsigned short* __restrict__ esorted,
                                                   const int* __restrict__ rp,
                                                   const float* __restrict__ dinv,
                                                   const float* __restrict__ bias,
                                                   float* __restrict__ outp) {
    const int g = blockIdx.x & 63;           // %8 XCD invariant: all 4 slices of g share an XCD L2
    const int f0 = (blockIdx.x >> 6) * 16;
    const int r = threadIdx.x;               // one dst row per thread
    const int base = g * NPER;
    const float* __restrict__ hb = h + (size_t)base * HID + f0;
    const float* __restrict__ dvg = dinv + base;

    const float dv = dvg[r];
    const float* own = hb + (size_t)r * HID;
    float4 acc0 = *(const float4*)(own);
    float4 acc1 = *(const float4*)(own + 4);
    float4 acc2 = *(const float4*)(own + 8);
    float4 acc3 = *(const float4*)(own + 12);
    // self-loop: h[d]*dv now, final *dv makes it h[d]*dv^2
    acc0.x *= dv; acc0.y *= dv; acc0.z *= dv; acc0.w *= dv;
    acc1.x *= dv; acc1.y *= dv; acc1.z *= dv; acc1.w *= dv;
    acc2.x *= dv; acc2.y *= dv; acc2.z *= dv; acc2.w *= dv;
    acc3.x *= dv; acc3.y *= dv; acc3.z *= dv; acc3.w *= dv;

    const unsigned short* es = esorted + (size_t)g * ECAP;
    const int* rpg = rp + g * (NPER + 1);
    int p = rpg[r];
    const int pe = rpg[r + 1];

    for (; p < pe; p += 4) {
        uint2 w4 = *(const uint2*)(es + p);
        int s0 = (int)(w4.x & 0xFFFFu), s1 = (int)(w4.x >> 16);
        int s2 = (int)(w4.y & 0xFFFFu), s3 = (int)(w4.y >> 16);
        // clamp padding (ZROW) to a valid row, zero its coefficient
        int i0 = s0 < NPER ? s0 : 0, i1 = s1 < NPER ? s1 : 0;
        int i2 = s2 < NPER ? s2 : 0, i3 = s3 < NPER ? s3 : 0;
        float c0 = s0 < NPER ? dvg[i0] : 0.f;
        float c1 = s1 < NPER ? dvg[i1] : 0.f;
        float c2 = s2 < NPER ? dvg[i2] : 0.f;
        float c3 = s3 < NPER ? dvg[i3] : 0.f;
        const float* q0 = hb + (size_t)i0 * HID;
        const float* q1 = hb + (size_t)i1 * HID;
        const float* q2 = hb + (size_t)i2 * HID;
        const float* q3 = hb + (size_t)i3 * HID;
        float4 a00 = *(const float4*)(q0),     a01 = *(const float4*)(q0 + 4);
        float4 a02 = *(const float4*)(q0 + 8), a03 = *(const float4*)(q0 + 12);
        float4 b00 = *(const float4*)(q1),     b01 = *(const float4*)(q1 + 4);
        float4 b02 = *(const float4*)(q1 + 8), b03 = *(const float4*)(q1 + 12);
        float4 c00 = *(const float4*)(q2),     c01 = *(const float4*)(q2 + 4);
        float4 c02 = *(const float4*)(q2 + 8), c03 = *(const float4*)(q2 + 12);
        float4 d00 = *(const float4*)(q3),     d01 = *(const float4*)(q3 + 4);
        float4 d02 = *(const float4*)(q3 + 8), d03 = *(const float4*)(q3 + 12);

        acc0.x = fmaf(a00.x, c0, acc0.x); acc0.y = fmaf(a00.y, c0, acc0.y);
        acc0.z = fmaf(a00.z, c0, acc0.z); acc0.w = fmaf(a00.w, c0, acc0.w);
        acc1.x = fmaf(a01.x, c0, acc1.x); acc1.y = fmaf(a01.y, c0, acc1.y);
        acc1.z = fmaf(a01.z, c0, acc1.z); acc1.w = fmaf(a01.w, c0, acc1.w);
        acc2.x = fmaf(a02.x, c0, acc2.x); acc2.y = fmaf(a02.y, c0, acc2.y);
        acc2.z = fmaf(a02.z, c0, acc2.z); acc2.w = fmaf(a02.w, c0, acc2.w);
        acc3.x = fmaf(a03.x, c0, acc3.x); acc3.y = fmaf(a03.y, c0, acc3.y);
        acc3.z = fmaf(a03.z, c0, acc3.z); acc3.w = fmaf(a03.w, c0, acc3.w);

        acc0.x = fmaf(b00.x, c1, acc0.x); acc0.y = fmaf(b00.y, c1, acc0.y);
        acc0.z = fmaf(b00.z, c1, acc0.z); acc0.w = fmaf(b00.w, c1, acc0.w);
        acc1.x = fmaf(b01.x, c1, acc1.x); acc1.y = fmaf(b01.y, c1, acc1.y);
        acc1.z = fmaf(b01.z, c1, acc1.z); acc1.w = fmaf(b01.w, c1, acc1.w);
        acc2.x = fmaf(b02.x, c1, acc2.x); acc2.y = fmaf(b02.y, c1, acc2.y);
        acc2.z = fmaf(b02.z, c1, acc2.z); acc2.w = fmaf(b02.w, c1, acc2.w);
        acc3.x = fmaf(b03.x, c1, acc3.x); acc3.y = fmaf(b03.y, c1, acc3.y);
        acc3.z = fmaf(b03.z, c1, acc3.z); acc3.w = fmaf(b03.w, c1, acc3.w);

        acc0.x = fmaf(c00.x, c2, acc0.x); acc0.y = fmaf(c00.y, c2, acc0.y);
        acc0.z = fmaf(c00.z, c2, acc0.z); acc0.w = fmaf(c00.w, c2, acc0.w);
        acc1.x = fmaf(c01.x, c2, acc1.x); acc1.y = fmaf(c01.y, c2, acc1.y);
        acc1.z = fmaf(c01.z, c2, acc1.z); acc1.w = fmaf(c01.w, c2, acc1.w);
        acc2.x = fmaf(c02.x, c2, acc2.x); acc2.y = fmaf(c02.y, c2, acc2.y);
        acc2.z = fmaf(c02.z, c2, acc2.z); acc2.w = fmaf(c02.w, c2, acc2.w);
        acc3.x = fmaf(c03.x, c2, acc3.x); acc3.y = fmaf(c03.y, c2, acc3.y);
        acc3.z = fmaf(c03.z, c2, acc3.z); acc3.w = fmaf(c03.w, c2, acc3.w);

        acc0.x = fmaf(d00.x, c3, acc0.x); acc0.y = fmaf(d00.y, c3, acc0.y);
        acc0.z = fmaf(d00.z, c3, acc0.z); acc0.w = fmaf(d00.w, c3, acc0.w);
        acc1.x = fmaf(d01.x, c3, acc1.x); acc1.y = fmaf(d01.y, c3, acc1.y);
        acc1.z = fmaf(d01.z, c3, acc1.z); acc1.w = fmaf(d01.w, c3, acc1.w);
        acc2.x = fmaf(d02.x, c3, acc2.x); acc2.y = fmaf(d02.y, c3, acc2.y);
        acc2.z = fmaf(d02.z, c3, acc2.z); acc2.w = fmaf(d02.w, c3, acc2.w);
        acc3.x = fmaf(d03.x, c3, acc3.x); acc3.y = fmaf(d03.y, c3, acc3.y);
        acc3.z = fmaf(d03.z, c3, acc3.z); acc3.w = fmaf(d03.w, c3, acc3.w);
    }

    float4 bb0 = *(const float4*)(bias + f0);
    float4 bb1 = *(const float4*)(bias + f0 + 4);
    float4 bb2 = *(const float4*)(bias + f0 + 8);
    float4 bb3 = *(const float4*)(bias + f0 + 12);

    float4 o0, o1, o2, o3;
    o0.x = fmaxf(fmaf(acc0.x, dv, bb0.x), 0.f); o0.y = fmaxf(fmaf(acc0.y, dv, bb0.y), 0.f);
    o0.z = fmaxf(fmaf(acc0.z, dv, bb0.z), 0.f); o0.w = fmaxf(fmaf(acc0.w, dv, bb0.w), 0.f);
    o1.x = fmaxf(fmaf(acc1.x, dv, bb1.x), 0.f); o1.y = fmaxf(fmaf(acc1.y, dv, bb1.y), 0.f);
    o1.z = fmaxf(fmaf(acc1.z, dv, bb1.z), 0.f); o1.w = fmaxf(fmaf(acc1.w, dv, bb1.w), 0.f);
    o2.x = fmaxf(fmaf(acc2.x, dv, bb2.x), 0.f); o2.y = fmaxf(fmaf(acc2.y, dv, bb2.y), 0.f);
    o2.z = fmaxf(fmaf(acc2.z, dv, bb2.z), 0.f); o2.w = fmaxf(fmaf(acc2.w, dv, bb2.w), 0.f);
    o3.x = fmaxf(fmaf(acc3.x, dv, bb3.x), 0.f); o3.y = fmaxf(fmaf(acc3.y, dv, bb3.y), 0.f);
    o3.z = fmaxf(fmaf(acc3.z, dv, bb3.z), 0.f); o3.w = fmaxf(fmaf(acc3.w, dv, bb3.w), 0.f);

    float* op = outp + (size_t)(base + r) * HID + f0;
    *(float4*)(op)      = o0;
    *(float4*)(op + 4)  = o1;
    *(float4*)(op + 8)  = o2;
    *(float4*)(op + 12) = o3;
}

// ---------------------------------------------------------------- fused DMoN phase 1 (verified, unchanged)
__global__ __launch_bounds__(256) void pool1_kernel(const float* __restrict__ h,
                                                    const float* __restrict__ Wp,
                                                    const float* __restrict__ bp,
                                                    float* __restrict__ xpart) {
    __shared__ float xs[128][HID + 1];
    __shared__ float ss[128][KCLUS + 1];
    __shared__ float wp[KCLUS][HID];
    __shared__ float bps[KCLUS];
    const int g = blockIdx.x >> 3;
    const int c = blockIdx.x & 7;
    const int t = threadIdx.x;
    const float* hb = h + ((size_t)g * NPER + c * 128) * HID;

    for (int i = t; i < 128 * HID / 4; i += 256) {
        float4 v = ((const float4*)hb)[i];
        int row = i >> 4, col = (i & 15) * 4;
        xs[row][col] = v.x; xs[row][col + 1] = v.y; xs[row][col + 2] = v.z; xs[row][col + 3] = v.w;
    }
    for (int i = t; i < KCLUS * HID; i += 256) wp[i >> 6][i & 63] = Wp[i];
    if (t < KCLUS) bps[t] = bp[t];
    __syncthreads();

    if (t < 128) {
        float lg[KCLUS];
        float mx = -1e30f;
#pragma unroll
        for (int k = 0; k < KCLUS; ++k) {
            float a = bps[k];
#pragma unroll 8
            for (int hh = 0; hh < HID; ++hh) a = fmaf(xs[t][hh], wp[k][hh], a);
            lg[k] = a;
            mx = fmaxf(mx, a);
        }
        float sum = 0.f;
#pragma unroll
        for (int k = 0; k < KCLUS; ++k) {
            lg[k] = __expf(lg[k] - mx);
            sum += lg[k];
        }
        float inv = 1.0f / sum;
#pragma unroll
        for (int k = 0; k < KCLUS; ++k) ss[t][k] = lg[k] * inv;
    }
    __syncthreads();

    const int hcol = t & 63;
    const int k0 = (t >> 6) * 4;
    float a0 = 0.f, a1 = 0.f, a2 = 0.f, a3 = 0.f;
#pragma unroll 8
    for (int n = 0; n < 128; ++n) {
        float xv = xs[n][hcol];
        a0 = fmaf(ss[n][k0 + 0], xv, a0);
        a1 = fmaf(ss[n][k0 + 1], xv, a1);
        a2 = fmaf(ss[n][k0 + 2], xv, a2);
        a3 = fmaf(ss[n][k0 + 3], xv, a3);
    }
    float* xp = xpart + (((size_t)(g * 8 + c)) * KCLUS + k0) * HID + hcol;
    xp[0] = a0; xp[HID] = a1; xp[2 * HID] = a2; xp[3 * HID] = a3;
}

// ---------------------------------------------------------------- DMoN phase 2 (verified, unchanged)
__global__ __launch_bounds__(256) void pool2_kernel(const float* __restrict__ xpart,
                                                    const float* __restrict__ Wl,
                                                    const float* __restrict__ bl,
                                                    float* __restrict__ out) {
    __shared__ float xp[KCLUS][HID + 1];
    __shared__ float outm[HID];
    const int g = blockIdx.x;
    const int t = threadIdx.x;
    const int hcol = t & 63;
    const int k0 = (t >> 6) * 4;
    const float* base = xpart + (size_t)g * 8 * KCLUS * HID;

    float a[4] = {};
#pragma unroll
    for (int c = 0; c < 8; ++c)
#pragma unroll
        for (int j = 0; j < 4; ++j)
            a[j] += base[(c * KCLUS + k0 + j) * HID + hcol];

    const float sc = 1.0507009873554805f, al = 1.6732632423543772f;
#pragma unroll
    for (int j = 0; j < 4; ++j) {
        float v = a[j];
        xp[k0 + j][hcol] = v > 0.f ? sc * v : sc * al * (__expf(v) - 1.f);
    }
    __syncthreads();

    if (t < HID) {
        float m = 0.f;
#pragma unroll
        for (int k = 0; k < KCLUS; ++k) m += xp[k][t];
        outm[t] = m * (1.0f / KCLUS);
    }
    __syncthreads();

    if (t < NCLS) {
        float acc = bl[t];
#pragma unroll 8
        for (int hh = 0; hh < HID; ++hh) acc = fmaf(outm[hh], Wl[t * HID + hh], acc);
        out[g * NCLS + t] = acc;
    }
}

// ---------------------------------------------------------------- launch
extern "C" void kernel_launch(void* const* d_in, const int* in_sizes, int n_in,
                              void* d_out, int out_size, void* d_ws, size_t ws_size,
                              hipStream_t stream) {
    const float* x  = (const float*)d_in[0];
    const int* eidx = (const int*)d_in[1];
    const float* W1 = (const float*)d_in[3];
    const float* b1 = (const float*)d_in[4];
    const float* W2 = (const float*)d_in[5];
    const float* b2 = (const float*)d_in[6];
    const float* Wp = (const float*)d_in[7];
    const float* bp = (const float*)d_in[8];
    const float* Wl = (const float*)d_in[9];
    const float* bl = (const float*)d_in[10];
    float* out = (float*)d_out;

    const int E = in_sizes[1] / 2;
    const int* src = eidx;
    const int* dst = eidx + E;

    // workspace layout: ecnt | gedges | esorted | rp | dinv | A | Bf | xpart
    char* w = (char*)d_ws;
    int*            ecnt    = (int*)w;            w += 256;
    int*            gedges  = (int*)w;            w += (size_t)NGRAPH * ECAP * 4;
    unsigned short* esorted = (unsigned short*)w; w += (size_t)NGRAPH * ECAP * 2;
    int*            rp      = (int*)w;            w += (size_t)NGRAPH * (NPER + 1) * 4;
    float*          dinv    = (float*)w;          w += (size_t)N_NODES * 4;
    float*          A       = (float*)w;          w += (size_t)N_NODES * HID * 4;
    float*          Bf      = (float*)w;          w += (size_t)N_NODES * HID * 4;
    float*          xpart   = (float*)w;          w += (size_t)NGRAPH * 8 * KCLUS * HID * 4;

    hipMemsetAsync(ecnt, 0, 256, stream);

    // linear1 || bucket (independent) in one dispatch
    const int nbucket = (E + 1023) / 1024;
    front_kernel<<<LIN_BLOCKS + nbucket, 256, 0, stream>>>(x, W1, A, src, dst, ecnt, gedges, E);

    // distributed CSR build
    scatter_kernel<<<NGRAPH * 8, 1024, 0, stream>>>(gedges, ecnt, rp, esorted, dinv);

    // conv1 aggregation (L2-direct): A -> Bf
    agg_kernel<<<NGRAPH * 4, 1024, 0, stream>>>(A, esorted, rp, dinv, b1, Bf);

    // conv2: Bf -> A -> Bf
    linear_kernel<HID><<<N_NODES / 128, 256, 0, stream>>>(Bf, W2, A);
    agg_kernel<<<NGRAPH * 4, 1024, 0, stream>>>(A, esorted, rp, dinv, b2, Bf);

    // DMoN pooling + classifier
    pool1_kernel<<<NGRAPH * 8, 256, 0, stream>>>(Bf, Wp, bp, xpart);
    pool2_kernel<<<NGRAPH, 256, 0, stream>>>(xpart, Wl, bl, out);
}

// Round 6
// 226.999 us; speedup vs baseline: 1.2233x; 1.2233x over previous
//
#include <hip/hip_runtime.h>
#include <cstddef>

#define N_NODES 65536
#define NPER    1024
#define NGRAPH  64
#define HID     64
#define IN_F    128
#define KCLUS   16
#define NCLS    10
#define NCAP    64      // per-node neighbor capacity (deg ~ Poisson(16); overflow prob ~1e-20)
#define HSTRIDE 12      // node-major LDS row stride (48 B, 16B-aligned)
#define LIN_BLOCKS 512  // N_NODES/128 tiles for the linear part of front_kernel

// ================================================================ GEMM tile core (verified round-0/3)
template <int K>
__device__ __forceinline__ void gemm_tile(const float* __restrict__ X,
                                          const float* __restrict__ W,
                                          float* __restrict__ Y,
                                          float (*xs)[68], float (*ws)[68],
                                          int block, int t) {
    const size_t row0 = (size_t)block * 128;
    const int rbase = t >> 3;   // 0..31
    const int cbase = t & 7;    // 0..7
    float acc[4][8] = {};

    for (int kc = 0; kc < K; kc += 64) {
        __syncthreads();
        for (int i = t; i < 128 * 16; i += 256) {   // X tile: 128 rows x 16 float4
            int row = i >> 4, k4 = (i & 15) << 2;
            *(float4*)&xs[row][k4] = *(const float4*)(X + (row0 + row) * K + kc + k4);
        }
        for (int i = t; i < 64 * 16; i += 256) {    // W tile: 64 rows x 16 float4
            int col = i >> 4, k4 = (i & 15) << 2;
            *(float4*)&ws[col][k4] = *(const float4*)(W + col * K + kc + k4);
        }
        __syncthreads();

#pragma unroll 4
        for (int k4 = 0; k4 < 64; k4 += 4) {
            float4 xr[4], wr[8];
#pragma unroll
            for (int rr = 0; rr < 4; ++rr) xr[rr] = *(const float4*)&xs[rbase + 32 * rr][k4];
#pragma unroll
            for (int cc = 0; cc < 8; ++cc) wr[cc] = *(const float4*)&ws[cbase + 8 * cc][k4];
#pragma unroll
            for (int rr = 0; rr < 4; ++rr)
#pragma unroll
                for (int cc = 0; cc < 8; ++cc) {
                    acc[rr][cc] = fmaf(xr[rr].x, wr[cc].x, acc[rr][cc]);
                    acc[rr][cc] = fmaf(xr[rr].y, wr[cc].y, acc[rr][cc]);
                    acc[rr][cc] = fmaf(xr[rr].z, wr[cc].z, acc[rr][cc]);
                    acc[rr][cc] = fmaf(xr[rr].w, wr[cc].w, acc[rr][cc]);
                }
        }
    }

#pragma unroll
    for (int rr = 0; rr < 4; ++rr)
#pragma unroll
        for (int cc = 0; cc < 8; ++cc)
            Y[(row0 + rbase + 32 * rr) * HID + cbase + 8 * cc] = acc[rr][cc];
}

// ---------------------------------------------------------------- front: linear1 (blocks 0..511) || single-pass edge build (blocks 512..)
// The edge build replaces the old bucket->histogram->scan->scatter chain:
// one global atomicAdd per edge claims a slot in the dst node's fixed-capacity
// neighbor list. deg[] doubles as the CSR "row length"; dinv is derived from it
// on the fly in agg. Edge order within a list races -- summation order only
// (verified tolerance-safe by rounds 0-5, which all raced the scatter too).
__global__ __launch_bounds__(256) void front_kernel(const float* __restrict__ X,
                                                    const float* __restrict__ W,
                                                    float* __restrict__ Y,
                                                    const int* __restrict__ src,
                                                    const int* __restrict__ dst,
                                                    int* __restrict__ deg,
                                                    unsigned short* __restrict__ es, int E) {
    __shared__ float xs[128][68];
    __shared__ float ws[64][68];
    const int t = threadIdx.x;

    if (blockIdx.x >= LIN_BLOCKS) {
        const int e0 = (blockIdx.x - LIN_BLOCKS) * 1024;
#pragma unroll
        for (int i = 0; i < 4; ++i) {
            int idx = e0 + i * 256 + t;
            if (idx < E) {
                int d = dst[idx], s = src[idx];
                int pos = atomicAdd(&deg[d], 1);
                if (pos < NCAP) es[(size_t)d * NCAP + pos] = (unsigned short)(s & 1023);
            }
        }
        return;
    }

    gemm_tile<IN_F>(X, W, Y, xs, ws, blockIdx.x, t);
}

// ---------------------------------------------------------------- dense linear (conv2): Y = X @ W^T (verified)
template <int K>
__global__ __launch_bounds__(256) void linear_kernel(const float* __restrict__ X,
                                                     const float* __restrict__ W,
                                                     float* __restrict__ Y) {
    __shared__ float xs[128][68];
    __shared__ float ws[64][68];
    gemm_tile<K>(X, W, Y, xs, ws, blockIdx.x, threadIdx.x);
}

// ---------------------------------------------------------------- pull-based aggregation (verified round-3 core, per-node list addressing)
// Differences from the verified agg: (1) edge list is es[node*NCAP ..], length
// deg[node] (clamped to NCAP), no rp/padding; tail (deg&3) handled by a scalar
// loop; (2) dinv computed on the fly from deg; (3) ZROW row dropped -> LDS
// 53248 B -> 3 blocks/CU (was 2), +50% resident waves for the gather.
__global__ __launch_bounds__(512) void agg_kernel(const float* __restrict__ h,
                                                  const unsigned short* __restrict__ es,
                                                  const int* __restrict__ deg,
                                                  const float* __restrict__ bias,
                                                  float* __restrict__ outp) {
    __shared__ float Hs[NPER * HSTRIDE];
    __shared__ float dl[NPER];
    const int g = blockIdx.x & 63;          // same-XCD grouping (%8 invariant)
    const int f0 = (blockIdx.x >> 6) * 8;
    const int t = threadIdx.x;
    const int base = g * NPER;

    for (int r = t; r < NPER; r += 512) {
        const float* hp = h + (size_t)(base + r) * HID + f0;
        float4 a = *(const float4*)hp;
        float4 b = *(const float4*)(hp + 4);
        float dv = rsqrtf((float)deg[base + r] + 1.0f);
        dl[r] = dv;
        float* row = &Hs[r * HSTRIDE];
        *(float4*)row = make_float4(a.x * dv, a.y * dv, a.z * dv, a.w * dv);
        *(float4*)(row + 4) = make_float4(b.x * dv, b.y * dv, b.z * dv, b.w * dv);
    }
    float bb[8];
#pragma unroll
    for (int j = 0; j < 8; ++j) bb[j] = bias[f0 + j];
    __syncthreads();

    for (int ld = t; ld < NPER; ld += 512) {
        const unsigned short* ep = es + (size_t)(base + ld) * NCAP;
        int dg = deg[base + ld];
        dg = dg < NCAP ? dg : NCAP;         // matches build-side drop (never hit in practice)
        const float* srow = &Hs[ld * HSTRIDE];
        float4 acc0 = *(const float4*)srow;         // self-loop: h*dv, final *dv -> h*dv^2
        float4 acc1 = *(const float4*)(srow + 4);
        float4 bcc0 = make_float4(0.f, 0.f, 0.f, 0.f);
        float4 bcc1 = make_float4(0.f, 0.f, 0.f, 0.f);

        int p = 0;
        const int p4 = dg & ~3;
        for (; p < p4; p += 4) {
            uint2 w4 = *(const uint2*)(ep + p);
            const float* r0 = &Hs[(int)(w4.x & 0xFFFFu) * HSTRIDE];
            const float* r1 = &Hs[(int)(w4.x >> 16) * HSTRIDE];
            const float* r2 = &Hs[(int)(w4.y & 0xFFFFu) * HSTRIDE];
            const float* r3 = &Hs[(int)(w4.y >> 16) * HSTRIDE];
            float4 a0 = *(const float4*)r0, a1 = *(const float4*)(r0 + 4);
            float4 b0 = *(const float4*)r1, b1 = *(const float4*)(r1 + 4);
            float4 c0v = *(const float4*)r2, c1v = *(const float4*)(r2 + 4);
            float4 d0 = *(const float4*)r3, d1 = *(const float4*)(r3 + 4);
            acc0.x += a0.x; acc0.y += a0.y; acc0.z += a0.z; acc0.w += a0.w;
            acc1.x += a1.x; acc1.y += a1.y; acc1.z += a1.z; acc1.w += a1.w;
            bcc0.x += b0.x; bcc0.y += b0.y; bcc0.z += b0.z; bcc0.w += b0.w;
            bcc1.x += b1.x; bcc1.y += b1.y; bcc1.z += b1.z; bcc1.w += b1.w;
            acc0.x += c0v.x; acc0.y += c0v.y; acc0.z += c0v.z; acc0.w += c0v.w;
            acc1.x += c1v.x; acc1.y += c1v.y; acc1.z += c1v.z; acc1.w += c1v.w;
            bcc0.x += d0.x; bcc0.y += d0.y; bcc0.z += d0.z; bcc0.w += d0.w;
            bcc1.x += d1.x; bcc1.y += d1.y; bcc1.z += d1.z; bcc1.w += d1.w;
        }
        for (; p < dg; ++p) {               // tail (<=3 scalar edges)
            const float* rr = &Hs[(int)ep[p] * HSTRIDE];
            float4 e0 = *(const float4*)rr, e1 = *(const float4*)(rr + 4);
            acc0.x += e0.x; acc0.y += e0.y; acc0.z += e0.z; acc0.w += e0.w;
            acc1.x += e1.x; acc1.y += e1.y; acc1.z += e1.z; acc1.w += e1.w;
        }
        acc0.x += bcc0.x; acc0.y += bcc0.y; acc0.z += bcc0.z; acc0.w += bcc0.w;
        acc1.x += bcc1.x; acc1.y += bcc1.y; acc1.z += bcc1.z; acc1.w += bcc1.w;

        const float dv = dl[ld];
        float4 o0, o1;
        o0.x = fmaxf(fmaf(acc0.x, dv, bb[0]), 0.f);
        o0.y = fmaxf(fmaf(acc0.y, dv, bb[1]), 0.f);
        o0.z = fmaxf(fmaf(acc0.z, dv, bb[2]), 0.f);
        o0.w = fmaxf(fmaf(acc0.w, dv, bb[3]), 0.f);
        o1.x = fmaxf(fmaf(acc1.x, dv, bb[4]), 0.f);
        o1.y = fmaxf(fmaf(acc1.y, dv, bb[5]), 0.f);
        o1.z = fmaxf(fmaf(acc1.z, dv, bb[6]), 0.f);
        o1.w = fmaxf(fmaf(acc1.w, dv, bb[7]), 0.f);
        float* op = outp + (size_t)(base + ld) * HID + f0;
        *(float4*)op = o0;
        *(float4*)(op + 4) = o1;
    }
}

// ---------------------------------------------------------------- fused DMoN phase 1 (verified, unchanged)
__global__ __launch_bounds__(256) void pool1_kernel(const float* __restrict__ h,
                                                    const float* __restrict__ Wp,
                                                    const float* __restrict__ bp,
                                                    float* __restrict__ xpart) {
    __shared__ float xs[128][HID + 1];
    __shared__ float ss[128][KCLUS + 1];
    __shared__ float wp[KCLUS][HID];
    __shared__ float bps[KCLUS];
    const int g = blockIdx.x >> 3;
    const int c = blockIdx.x & 7;
    const int t = threadIdx.x;
    const float* hb = h + ((size_t)g * NPER + c * 128) * HID;

    for (int i = t; i < 128 * HID / 4; i += 256) {
        float4 v = ((const float4*)hb)[i];
        int row = i >> 4, col = (i & 15) * 4;
        xs[row][col] = v.x; xs[row][col + 1] = v.y; xs[row][col + 2] = v.z; xs[row][col + 3] = v.w;
    }
    for (int i = t; i < KCLUS * HID; i += 256) wp[i >> 6][i & 63] = Wp[i];
    if (t < KCLUS) bps[t] = bp[t];
    __syncthreads();

    if (t < 128) {
        float lg[KCLUS];
        float mx = -1e30f;
#pragma unroll
        for (int k = 0; k < KCLUS; ++k) {
            float a = bps[k];
#pragma unroll 8
            for (int hh = 0; hh < HID; ++hh) a = fmaf(xs[t][hh], wp[k][hh], a);
            lg[k] = a;
            mx = fmaxf(mx, a);
        }
        float sum = 0.f;
#pragma unroll
        for (int k = 0; k < KCLUS; ++k) {
            lg[k] = __expf(lg[k] - mx);
            sum += lg[k];
        }
        float inv = 1.0f / sum;
#pragma unroll
        for (int k = 0; k < KCLUS; ++k) ss[t][k] = lg[k] * inv;
    }
    __syncthreads();

    const int hcol = t & 63;
    const int k0 = (t >> 6) * 4;
    float a0 = 0.f, a1 = 0.f, a2 = 0.f, a3 = 0.f;
#pragma unroll 8
    for (int n = 0; n < 128; ++n) {
        float xv = xs[n][hcol];
        a0 = fmaf(ss[n][k0 + 0], xv, a0);
        a1 = fmaf(ss[n][k0 + 1], xv, a1);
        a2 = fmaf(ss[n][k0 + 2], xv, a2);
        a3 = fmaf(ss[n][k0 + 3], xv, a3);
    }
    float* xp = xpart + (((size_t)(g * 8 + c)) * KCLUS + k0) * HID + hcol;
    xp[0] = a0; xp[HID] = a1; xp[2 * HID] = a2; xp[3 * HID] = a3;
}

// ---------------------------------------------------------------- DMoN phase 2 (verified, unchanged)
__global__ __launch_bounds__(256) void pool2_kernel(const float* __restrict__ xpart,
                                                    const float* __restrict__ Wl,
                                                    const float* __restrict__ bl,
                                                    float* __restrict__ out) {
    __shared__ float xp[KCLUS][HID + 1];
    __shared__ float outm[HID];
    const int g = blockIdx.x;
    const int t = threadIdx.x;
    const int hcol = t & 63;
    const int k0 = (t >> 6) * 4;
    const float* base = xpart + (size_t)g * 8 * KCLUS * HID;

    float a[4] = {};
#pragma unroll
    for (int c = 0; c < 8; ++c)
#pragma unroll
        for (int j = 0; j < 4; ++j)
            a[j] += base[(c * KCLUS + k0 + j) * HID + hcol];

    const float sc = 1.0507009873554805f, al = 1.6732632423543772f;
#pragma unroll
    for (int j = 0; j < 4; ++j) {
        float v = a[j];
        xp[k0 + j][hcol] = v > 0.f ? sc * v : sc * al * (__expf(v) - 1.f);
    }
    __syncthreads();

    if (t < HID) {
        float m = 0.f;
#pragma unroll
        for (int k = 0; k < KCLUS; ++k) m += xp[k][t];
        outm[t] = m * (1.0f / KCLUS);
    }
    __syncthreads();

    if (t < NCLS) {
        float acc = bl[t];
#pragma unroll 8
        for (int hh = 0; hh < HID; ++hh) acc = fmaf(outm[hh], Wl[t * HID + hh], acc);
        out[g * NCLS + t] = acc;
    }
}

// ---------------------------------------------------------------- launch
extern "C" void kernel_launch(void* const* d_in, const int* in_sizes, int n_in,
                              void* d_out, int out_size, void* d_ws, size_t ws_size,
                              hipStream_t stream) {
    const float* x  = (const float*)d_in[0];
    const int* eidx = (const int*)d_in[1];
    const float* W1 = (const float*)d_in[3];
    const float* b1 = (const float*)d_in[4];
    const float* W2 = (const float*)d_in[5];
    const float* b2 = (const float*)d_in[6];
    const float* Wp = (const float*)d_in[7];
    const float* bp = (const float*)d_in[8];
    const float* Wl = (const float*)d_in[9];
    const float* bl = (const float*)d_in[10];
    float* out = (float*)d_out;

    const int E = in_sizes[1] / 2;
    const int* src = eidx;
    const int* dst = eidx + E;

    // workspace layout: deg | es | A | Bf | xpart
    char* w = (char*)d_ws;
    int*            deg   = (int*)w;            w += (size_t)N_NODES * 4;
    unsigned short* es    = (unsigned short*)w; w += (size_t)N_NODES * NCAP * 2;
    float*          A     = (float*)w;          w += (size_t)N_NODES * HID * 4;
    float*          Bf    = (float*)w;          w += (size_t)N_NODES * HID * 4;
    float*          xpart = (float*)w;          w += (size_t)NGRAPH * 8 * KCLUS * HID * 4;

    hipMemsetAsync(deg, 0, (size_t)N_NODES * 4, stream);

    // linear1 || single-pass edge-list build (independent) in one dispatch
    const int nbuild = (E + 1023) / 1024;
    front_kernel<<<LIN_BLOCKS + nbuild, 256, 0, stream>>>(x, W1, A, src, dst, deg, es, E);

    // conv1 aggregation: A -> Bf
    agg_kernel<<<NGRAPH * 8, 512, 0, stream>>>(A, es, deg, b1, Bf);

    // conv2: Bf -> A -> Bf
    linear_kernel<HID><<<N_NODES / 128, 256, 0, stream>>>(Bf, W2, A);
    agg_kernel<<<NGRAPH * 8, 512, 0, stream>>>(A, es, deg, b2, Bf);

    // DMoN pooling + classifier
    pool1_kernel<<<NGRAPH * 8, 256, 0, stream>>>(Bf, Wp, bp, xpart);
    pool2_kernel<<<NGRAPH, 256, 0, stream>>>(xpart, Wl, bl, out);
}